// Round 20
// baseline (91.025 us; speedup 1.0000x reference)
//
#include <hip/hip_runtime.h>
#include <math.h>

#define T_ 512
#define D_ 512
#define H_ 8
#define N_ 64
#define A_ 65
#define HN_ 512
#define HA_ 520
#define QS_ 66            // Q row stride (f32 storage, f64-computed)
#define VS_ 66            // V row stride (f32)
#define KTS_ 512          // K^T / V^T row stride
#define SYS_ 68           // sYm row stride (16B-aligned float4 reads)
#define EPS_ 1e-6
#define EPSF_ 1e-6f
#define TINY_ 1e-15
#define IT 8              // query rows per attention block (panel traffic /2 vs IT=4)
#define PTT 4             // rows per proj thread (per wave)
#define RPB_ 16           // rows per proj block
#define BN_ 64            // proj cols per block (= one head)
#define CH_ 64            // proj d-chunk
#define NCH_ (D_/CH_)     // 8
#define CTT 2             // rows per out thread

__device__ __forceinline__ double wsumd(double v){
#pragma unroll
  for (int o=32;o;o>>=1) v += __shfl_xor(v,o);
  return v;
}
__device__ __forceinline__ float wsumf(float v){
#pragma unroll
  for (int o=32;o;o>>=1) v += __shfl_xor(v,o);
  return v;
}
__device__ __forceinline__ float wmaxf(float v){
#pragma unroll
  for (int o=32;o;o>>=1) v = fmaxf(v,__shfl_xor(v,o));
  return v;
}
// fast acosh: caller clamps x >= 1+eps; log(x + sqrt(x^2-1)) via native v_log/v_sqrt
__device__ __forceinline__ float facoshf(float x){
  return __logf(x + sqrtf(fmaf(x,x,-1.f)));
}

__global__ void k_fill(float* __restrict__ out, float val){
  int i = blockIdx.x*256 + threadIdx.x;
  if (i < T_*D_) out[i] = val;
}

// ---------------- kernel 1: proj GEMM (r14 structure) + in-LDS trig + f64 lift (r18-exact)
__global__ __launch_bounds__(256) void k_projlift(
    const float* __restrict__ x,
    const float* __restrict__ Wq, const float* __restrict__ bq,
    const float* __restrict__ Wk, const float* __restrict__ bk,
    const float* __restrict__ Wv, const float* __restrict__ bv,
    float* __restrict__ Qf, float* __restrict__ KTf,
    float* __restrict__ Vf, float* __restrict__ VTf){
  __shared__ float sW[2][CH_*BN_];             // 2 x 16KB
  __shared__ double2 sTrig[RPB_*32];           // 8KB: (cos,sin) for (t-t0b, fi)
  int mode = blockIdx.y;                       // 0=Q(rope),1=K(rope),2=V
  const float* W  = (mode==0)?Wq:((mode==1)?Wk:Wv);
  const float* bb = (mode==0)?bq:((mode==1)?bk:bv);
  int tid = threadIdx.x;
  int lane = tid & 63;
  int h = blockIdx.x;                          // head = column block
  int n = lane;
  int t0b = blockIdx.z*RPB_;
  int t0 = __builtin_amdgcn_readfirstlane(t0b + ((tid>>6)<<2));
  int srr = tid >> 4;
  int scc = (tid*4) & 63;

  // in-block trig table (modes 0,1 only; hides under staging stall)
  if (mode < 2){
#pragma unroll
    for (int p=0;p<2;p++){
      int e = tid + p*256;                     // e = lt*32 + fi, lt in [0,16)
      int lt = e >> 5, fi = e & 31;
      double inv_f = 1.0 / pow(10000.0, (double)(2*fi)*(1.0/64.0));
      double ang = (double)(t0b + lt) * inv_f;
      sTrig[e] = make_double2(cos(ang), sin(ang));
    }
  }

  float acc[PTT];
#pragma unroll
  for (int i=0;i<PTT;i++) acc[i]=0.f;

  // prologue: stage chunk 0
  {
    float4 st[4];
#pragma unroll
    for (int k=0;k<4;k++)
      st[k] = *reinterpret_cast<const float4*>(W + (size_t)(k*16+srr)*HN_ + h*BN_ + scc);
#pragma unroll
    for (int k=0;k<4;k++)
      *reinterpret_cast<float4*>(&sW[0][k*1024 + tid*4]) = st[k];
  }
  __syncthreads();

  const float* xr = x + (size_t)t0*D_;
#pragma unroll 1
  for (int ch=0; ch<NCH_; ++ch){
    float4 st[4];
    if (ch+1 < NCH_){
#pragma unroll
      for (int k=0;k<4;k++)
        st[k] = *reinterpret_cast<const float4*>(
            W + (size_t)((ch+1)*CH_ + k*16+srr)*HN_ + h*BN_ + scc);
    }
    const float* sb = &sW[ch&1][0];
    int d0 = ch*CH_;
#pragma unroll 8
    for (int r=0;r<CH_;r++){
      float wd = sb[r*BN_ + lane];
#pragma unroll
      for (int i=0;i<PTT;i++)
        acc[i] = fmaf(xr[(size_t)i*D_ + d0 + r], wd, acc[i]);
    }
    if (ch+1 < NCH_){
#pragma unroll
      for (int k=0;k<4;k++)
        *reinterpret_cast<float4*>(&sW[(ch+1)&1][k*1024 + tid*4]) = st[k];
    }
    __syncthreads();
  }

  float bias = bb[h*BN_ + n];
#pragma unroll 1
  for (int i=0;i<PTT;i++){
    int t = t0 + i;
    double v = (double)(acc[i] + bias);
    if (mode < 2){
      const double2 cs2 = sTrig[(t - t0b)*32 + (n&31)];
      double vp = __shfl_xor(v, 32);
      double rot = (n<32) ? -vp : vp;
      v = v*cs2.x + rot*cs2.y;
    }
    // f64 lift (r12 lesson: must stay f64-computed; f32 storage safe)
    double ss = wsumd(v*v);
    double vn = sqrt(fmax(ss, TINY_));
    double e  = exp(vn);
    double ei = 1.0/e;
    double ch2 = 0.5*(e+ei);
    double s  = (0.5*(e-ei))/vn;               // sinh(vn)/vn
    double xx = s*s*ss - ch2*ch2;              // sum y^2 - ch^2 (exact algebra)
    double scale = sqrt(fmax(fabs(xx), TINY_));
    float y0 = (float)fabs(ch2/scale);
    float ya = (float)(s*v/scale);
    if (mode==0){
      float* o = Qf + (size_t)h*T_*QS_ + (size_t)t*QS_;
      if (n==0) o[0] = y0;
      o[n+1] = ya;
    } else if (mode==1){
      float* o = KTf + (size_t)h*66*KTS_ + t;
      if (n==0) o[0] = y0;
      o[(size_t)(n+1)*KTS_] = ya;
    } else {
      float* o = Vf + (size_t)h*T_*VS_ + (size_t)t*VS_;
      if (n==0) o[0] = y0;
      o[n+1] = ya;
      float* ot = VTf + (size_t)h*66*KTS_ + t;
      if (n==0) ot[0] = y0;
      ot[(size_t)(n+1)*KTS_] = ya;
    }
  }
}

// ---------------- kernel 2: attention; IT=8 + MERGED K^T/V^T dot phase
// (panel re-reads halved vs r19; avf carried across softmax in registers)
__global__ __launch_bounds__(256) void k_attnF(
    const float* __restrict__ Qf, const float* __restrict__ KTf,
    const float* __restrict__ VTf, const float* __restrict__ Vf,
    const float* __restrict__ anchor, float* __restrict__ Z){
  __shared__ float  sYf[IT][QS_];     // Q rows f32 (epilogue casts to f64)
  __shared__ float  sYm[IT][SYS_];    // sign-folded f32, pads 0
  __shared__ float  s_w[IT][T_];      // scores -> attn -> w
  __shared__ double sA[A_];
  __shared__ float  s_red[4][IT];     // cY partials
  __shared__ float  s_part[4][IT][64];// w@V lane partials
  __shared__ float  s_p64[4][IT];     // w@V dim-64 partials

  int h = blockIdx.x, i0 = blockIdx.y*IT, tid = threadIdx.x;
  int wv = tid>>6, lane = tid&63;
  const float* Qp = Qf  + (size_t)h*T_*QS_;
  const float* KT = KTf + (size_t)h*66*KTS_;
  const float* VT = VTf + (size_t)h*66*KTS_;
  const float* Vp = Vf  + (size_t)h*T_*VS_;

  for (int f=tid; f<IT*QS_; f+=256){
    int i=f/QS_, a=f-i*QS_;
    sYf[i][a] = (a<A_) ? Qp[(size_t)(i0+i)*QS_ + a] : 0.f;
  }
  for (int f=tid; f<IT*SYS_; f+=256){
    int i=f/SYS_, a=f-i*SYS_;
    float v = (a<A_) ? Qp[(size_t)(i0+i)*QS_ + a] : 0.f;
    sYm[i][a] = (a==0) ? v : -v;
  }
  if (tid < A_) sA[tid] = (double)anchor[tid];
  __syncthreads();

  int j0 = tid, j1 = tid + 256;
  float avf0[IT], avf1[IT];           // alpha_yv, carried across softmax
  // ---- stage B (merged): alpha_qk AND alpha_yv via K^T/V^T in one pass
  {
    float aq0[IT], aq1[IT], av0[IT], av1[IT];
#pragma unroll
    for (int i=0;i<IT;i++){ aq0[i]=0.f; aq1[i]=0.f; av0[i]=0.f; av1[i]=0.f; }
    for (int a4=0; a4<16; a4++){
      int a = a4*4;
      float k00=KT[(size_t)(a+0)*KTS_+j0], k01=KT[(size_t)(a+1)*KTS_+j0];
      float k02=KT[(size_t)(a+2)*KTS_+j0], k03=KT[(size_t)(a+3)*KTS_+j0];
      float k10=KT[(size_t)(a+0)*KTS_+j1], k11=KT[(size_t)(a+1)*KTS_+j1];
      float k12=KT[(size_t)(a+2)*KTS_+j1], k13=KT[(size_t)(a+3)*KTS_+j1];
      float v00=VT[(size_t)(a+0)*KTS_+j0], v01=VT[(size_t)(a+1)*KTS_+j0];
      float v02=VT[(size_t)(a+2)*KTS_+j0], v03=VT[(size_t)(a+3)*KTS_+j0];
      float v10=VT[(size_t)(a+0)*KTS_+j1], v11=VT[(size_t)(a+1)*KTS_+j1];
      float v12=VT[(size_t)(a+2)*KTS_+j1], v13=VT[(size_t)(a+3)*KTS_+j1];
#pragma unroll
      for (int i=0;i<IT;i++){
        float4 ym = *reinterpret_cast<const float4*>(&sYm[i][a]);
        aq0[i] = fmaf(ym.w,k03,fmaf(ym.z,k02,fmaf(ym.y,k01,fmaf(ym.x,k00,aq0[i]))));
        aq1[i] = fmaf(ym.w,k13,fmaf(ym.z,k12,fmaf(ym.y,k11,fmaf(ym.x,k10,aq1[i]))));
        av0[i] = fmaf(ym.w,v03,fmaf(ym.z,v02,fmaf(ym.y,v01,fmaf(ym.x,v00,av0[i]))));
        av1[i] = fmaf(ym.w,v13,fmaf(ym.z,v12,fmaf(ym.y,v11,fmaf(ym.x,v10,av1[i]))));
      }
    }
    float kt0 = KT[(size_t)64*KTS_+j0], kt1 = KT[(size_t)64*KTS_+j1];
    float vt0 = VT[(size_t)64*KTS_+j0], vt1 = VT[(size_t)64*KTS_+j1];
#pragma unroll
    for (int i=0;i<IT;i++){
      float a0 = fmaf(sYm[i][64], kt0, aq0[i]);
      float a1 = fmaf(sYm[i][64], kt1, aq1[i]);
      float d0 = facoshf(fmaxf(a0, 1.f+EPSF_));
      float d1 = facoshf(fmaxf(a1, 1.f+EPSF_));
      s_w[i][j0] = -d0*d0;
      s_w[i][j1] = -d1*d1;
      avf0[i] = fmaf(sYm[i][64], vt0, av0[i]);
      avf1[i] = fmaf(sYm[i][64], vt1, av1[i]);
    }
  }
  __syncthreads();

  // ---- stage C: softmax (f32); wave wv owns rows 2wv, 2wv+1
  for (int ii=0; ii<2; ii++){
    int i = wv*2 + ii;
    float m = -INFINITY;
#pragma unroll
    for (int kk=0;kk<8;kk++) m = fmaxf(m, s_w[i][lane+64*kk]);
    m = wmaxf(m);
    float e[8], sum=0.f;
#pragma unroll
    for (int kk=0;kk<8;kk++){ e[kk]=__expf(s_w[i][lane+64*kk]-m); sum+=e[kk]; }
    sum = wsumf(sum);
    float inv = 1.f/sum;
#pragma unroll
    for (int kk=0;kk<8;kk++) s_w[i][lane+64*kk] = e[kk]*inv;
  }
  __syncthreads();

  // ---- stage B2 (pure VALU): w = attn*dist/un0; cY partials
  {
    const float inv_un0 = 3.16227766016838e7f;  // 1/sqrt(TINY); mink(u,u)<0 proven r4-r19
    float cyp[IT];
#pragma unroll
    for (int i=0;i<IT;i++){
      float at0 = s_w[i][j0], at1 = s_w[i][j1];
      float d0 = facoshf(fmaxf(avf0[i], 1.f+EPSF_));
      float d1 = facoshf(fmaxf(avf1[i], 1.f+EPSF_));
      float w0 = at0*d0*inv_un0;
      float w1 = at1*d1*inv_un0;
      s_w[i][j0] = w0;
      s_w[i][j1] = w1;
      cyp[i] = fmaf(w0, avf0[i], w1*avf1[i]);
    }
#pragma unroll
    for (int i=0;i<IT;i++){
      float r = wsumf(cyp[i]);
      if (lane==0) s_red[wv][i] = r;
    }
  }
  __syncthreads();

  // ---- stage D: w @ V, j-split (wave wv owns 128 j for ALL rows), j-quad float4 w reads
  {
    float pL[IT], p64r[IT];
#pragma unroll
    for (int i=0;i<IT;i++){ pL[i]=0.f; p64r[i]=0.f; }
    int jb = wv*128;
    for (int jj=0; jj<128; jj+=4){
      int j = jb + jj;
      float vA = Vp[(size_t)(j+0)*VS_ + lane];
      float vB = Vp[(size_t)(j+1)*VS_ + lane];
      float vC = Vp[(size_t)(j+2)*VS_ + lane];
      float vD = Vp[(size_t)(j+3)*VS_ + lane];
#pragma unroll
      for (int i=0;i<IT;i++){
        float4 w4 = *reinterpret_cast<const float4*>(&s_w[i][j]);
        pL[i] = fmaf(w4.w,vD,fmaf(w4.z,vC,fmaf(w4.y,vB,fmaf(w4.x,vA,pL[i]))));
      }
    }
#pragma unroll
    for (int cc=0; cc<2; cc++){
      int j = jb + cc*64 + lane;
      float v64 = VT[(size_t)64*KTS_ + j];
#pragma unroll
      for (int i=0;i<IT;i++) p64r[i] = fmaf(s_w[i][j], v64, p64r[i]);
    }
#pragma unroll
    for (int i=0;i<IT;i++){
      s_part[wv][i][lane] = pL[i];
      float r = wsumf(p64r[i]);
      if (lane==0) s_p64[wv][i] = r;
    }
  }
  __syncthreads();

  // ---- epilogue (f64 — deep mink cancellation; proven r6-r19); rows 2wv, 2wv+1
  for (int ii=0; ii<2; ii++){
    int r = wv*2 + ii;
    double Yl  = (double)sYf[r][lane];
    double Y64 = (double)sYf[r][64];
    double cy = (double)s_red[0][r]+(double)s_red[1][r]+(double)s_red[2][r]+(double)s_red[3][r];
    double aL = (double)s_part[0][r][lane]+(double)s_part[1][r][lane]
              + (double)s_part[2][r][lane]+(double)s_part[3][r][lane];
    double a64 = (double)s_p64[0][r]+(double)s_p64[1][r]+(double)s_p64[2][r]+(double)s_p64[3][r];
    double ua  = fma(cy, Yl,  aL);
    double u64 = fma(cy, Y64, a64);
    double c2 = (lane==0) ? fma(u64,u64, -ua*ua) : ua*ua;
    double mv = wsumd(c2);
    double vn = sqrt(fmax(mv, TINY_));
    double ch = cosh(vn);
    double sh = sinh(vn)/fmax(vn, TINY_);
    double ya  = fma(ch, Yl,  sh*ua);
    double y64 = fma(ch, Y64, sh*u64);
    double c3 = (lane==0) ? fma(y64,y64, -ya*ya) : ya*ya;
    double px = wsumd(c3);
    double scale = sqrt(fmax(fabs(px), TINY_));
    double Pa  = ya/scale; if (lane==0) Pa = fabs(Pa);
    double P64 = y64/scale;
    double sAl = sA[lane];
    double azc = (lane==0) ? fma(sAl, Pa, -sA[64]*P64) : (-sAl*Pa);
    double az = wsumd(azc);
    double dz = acosh(fmax(az, 1.0+EPS_));
    double uza  = fma(az, sAl,    Pa);
    double uz64 = fma(az, sA[64], P64);
    double c4v = (lane==0) ? fma(uz64,uz64, -uza*uza) : uza*uza;
    double mz = wsumd(c4v);
    double unz = sqrt(fmax(mz, TINY_));
    double fz = dz/fmax(unz, TINY_);
    float* Zr = Z + (size_t)(i0+r)*HA_ + h*A_;
    Zr[lane] = (float)(fz*uza);
    if (lane==0) Zr[64] = (float)(fz*uz64);
  }
}

// ---------------- kernel 3: out = Z @ Wo + bo (f32); CTT=2 (r14 proven)
__global__ __launch_bounds__(256) void k_outD(
    const float* __restrict__ Zb, const float* __restrict__ Wo,
    const float* __restrict__ bo, float* __restrict__ out){
  int c  = blockIdx.x*256 + threadIdx.x;
  int t0 = blockIdx.y*CTT;
  float acc[CTT];
#pragma unroll
  for (int i=0;i<CTT;i++) acc[i]=0.f;
  for (int k=0;k<HA_;k+=4){
    float w0 = Wo[(size_t)(k+0)*D_ + c];
    float w1 = Wo[(size_t)(k+1)*D_ + c];
    float w2 = Wo[(size_t)(k+2)*D_ + c];
    float w3 = Wo[(size_t)(k+3)*D_ + c];
#pragma unroll
    for (int i=0;i<CTT;i++){
      const float* zr = Zb + (size_t)(t0+i)*HA_;
      acc[i] = fmaf(zr[k+0], w0, acc[i]);
      acc[i] = fmaf(zr[k+1], w1, acc[i]);
      acc[i] = fmaf(zr[k+2], w2, acc[i]);
      acc[i] = fmaf(zr[k+3], w3, acc[i]);
    }
  }
  float bb = bo[c];
#pragma unroll
  for (int i=0;i<CTT;i++) out[(t0+i)*D_ + c] = acc[i] + bb;
}

extern "C" void kernel_launch(void* const* d_in, const int* in_sizes, int n_in,
                              void* d_out, int out_size, void* d_ws, size_t ws_size,
                              hipStream_t stream){
  float* out = (float*)d_out;

  bool ok = (n_in == 10) && (out_size == T_*D_)
    && in_sizes[0]==T_*D_ && in_sizes[1]==D_*HN_ && in_sizes[2]==HN_
    && in_sizes[3]==D_*HN_ && in_sizes[4]==HN_
    && in_sizes[5]==D_*HN_ && in_sizes[6]==HN_
    && in_sizes[7]==HA_*D_ && in_sizes[8]==D_ && in_sizes[9]==A_;
  if (!ok){ k_fill<<<1024,256,0,stream>>>(out, 1.0e12f); return; }

  const float* x      = (const float*)d_in[0];
  const float* Wq     = (const float*)d_in[1];
  const float* bq     = (const float*)d_in[2];
  const float* Wk     = (const float*)d_in[3];
  const float* bk     = (const float*)d_in[4];
  const float* Wv     = (const float*)d_in[5];
  const float* bv     = (const float*)d_in[6];
  const float* Wo     = (const float*)d_in[7];
  const float* bo     = (const float*)d_in[8];
  const float* anchor = (const float*)d_in[9];
  char* ws = (char*)d_ws;

  size_t zbytes  = (size_t)T_*HA_*sizeof(float);            // 1,064,960
  size_t qbytes  = (size_t)H_*T_*QS_*sizeof(float);         // 1,081,344
  size_t ktbytes = (size_t)H_*66*KTS_*sizeof(float);        // 1,081,344
  size_t vbytes  = (size_t)H_*T_*VS_*sizeof(float);         // 1,081,344
  size_t vtbytes = (size_t)H_*66*KTS_*sizeof(float);        // 1,081,344
  size_t need    = zbytes+qbytes+ktbytes+vbytes+vtbytes;    // 5,390,336 <= proven 7,569,408
  if (ws_size < need){ k_fill<<<1024,256,0,stream>>>(out, 2.0e12f); return; }

  float*  Zf = (float*)ws;
  float*  Qf = (float*)(ws + zbytes);
  float*  KT = (float*)(ws + zbytes + qbytes);
  float*  Vf = (float*)(ws + zbytes + qbytes + ktbytes);
  float*  VT = (float*)(ws + zbytes + qbytes + ktbytes + vbytes);

  k_projlift<<<dim3(H_,3,T_/RPB_), 256, 0, stream>>>(x, Wq,bq, Wk,bk, Wv,bv, Qf, KT, Vf, VT);
  k_attnF   <<<dim3(H_, T_/IT),    256, 0, stream>>>(Qf, KT, VT, Vf, anchor, Zf);
  k_outD    <<<dim3(2, T_/CTT),    256, 0, stream>>>(Zf, Wo, bo, out);
}

// Round 21
// 88.443 us; speedup vs baseline: 1.0292x; 1.0292x over previous
//
#include <hip/hip_runtime.h>
#include <math.h>

#define T_ 512
#define D_ 512
#define H_ 8
#define N_ 64
#define A_ 65
#define HN_ 512
#define HA_ 520
#define QS_ 66            // Q row stride (f32 storage, f64-computed)
#define VS_ 66            // V row stride (f32)
#define KTS_ 512          // K^T / V^T row stride
#define SYS_ 68           // sYm row stride (16B-aligned float4 reads)
#define EPS_ 1e-6
#define EPSF_ 1e-6f
#define TINY_ 1e-15
#define IT 4              // query rows per attention block (r19 proven best)
#define PTT 4             // rows per proj thread (per wave)
#define RPB_ 16           // rows per proj block
#define BN_ 64            // proj cols per block (= one head)
#define CH_ 64            // proj d-chunk
#define NCH_ (D_/CH_)     // 8
#define CTT 2             // rows per out thread

__device__ __forceinline__ double wsumd(double v){
#pragma unroll
  for (int o=32;o;o>>=1) v += __shfl_xor(v,o);
  return v;
}
__device__ __forceinline__ float wsumf(float v){
#pragma unroll
  for (int o=32;o;o>>=1) v += __shfl_xor(v,o);
  return v;
}
__device__ __forceinline__ float wmaxf(float v){
#pragma unroll
  for (int o=32;o;o>>=1) v = fmaxf(v,__shfl_xor(v,o));
  return v;
}
// fast acosh: caller clamps x >= 1+eps; log(x + sqrt(x^2-1)) via native v_log/v_sqrt
__device__ __forceinline__ float facoshf(float x){
  return __logf(x + sqrtf(fmaf(x,x,-1.f)));
}

__global__ void k_fill(float* __restrict__ out, float val){
  int i = blockIdx.x*256 + threadIdx.x;
  if (i < T_*D_) out[i] = val;
}

// ---------------- kernel 1: proj GEMM (r14 structure) + in-LDS trig + f64 lift (r18-exact)
__global__ __launch_bounds__(256) void k_projlift(
    const float* __restrict__ x,
    const float* __restrict__ Wq, const float* __restrict__ bq,
    const float* __restrict__ Wk, const float* __restrict__ bk,
    const float* __restrict__ Wv, const float* __restrict__ bv,
    float* __restrict__ Qf, float* __restrict__ KTf,
    float* __restrict__ Vf, float* __restrict__ VTf){
  __shared__ float sW[2][CH_*BN_];             // 2 x 16KB
  __shared__ double2 sTrig[RPB_*32];           // 8KB: (cos,sin) for (t-t0b, fi)
  int mode = blockIdx.y;                       // 0=Q(rope),1=K(rope),2=V
  const float* W  = (mode==0)?Wq:((mode==1)?Wk:Wv);
  const float* bb = (mode==0)?bq:((mode==1)?bk:bv);
  int tid = threadIdx.x;
  int lane = tid & 63;
  int h = blockIdx.x;                          // head = column block
  int n = lane;
  int t0b = blockIdx.z*RPB_;
  int t0 = __builtin_amdgcn_readfirstlane(t0b + ((tid>>6)<<2));
  int srr = tid >> 4;
  int scc = (tid*4) & 63;

  // in-block trig table (modes 0,1 only; hides under staging stall)
  if (mode < 2){
#pragma unroll
    for (int p=0;p<2;p++){
      int e = tid + p*256;                     // e = lt*32 + fi, lt in [0,16)
      int lt = e >> 5, fi = e & 31;
      double inv_f = 1.0 / pow(10000.0, (double)(2*fi)*(1.0/64.0));
      double ang = (double)(t0b + lt) * inv_f;
      sTrig[e] = make_double2(cos(ang), sin(ang));
    }
  }

  float acc[PTT];
#pragma unroll
  for (int i=0;i<PTT;i++) acc[i]=0.f;

  // prologue: stage chunk 0
  {
    float4 st[4];
#pragma unroll
    for (int k=0;k<4;k++)
      st[k] = *reinterpret_cast<const float4*>(W + (size_t)(k*16+srr)*HN_ + h*BN_ + scc);
#pragma unroll
    for (int k=0;k<4;k++)
      *reinterpret_cast<float4*>(&sW[0][k*1024 + tid*4]) = st[k];
  }
  __syncthreads();

  const float* xr = x + (size_t)t0*D_;
#pragma unroll 1
  for (int ch=0; ch<NCH_; ++ch){
    float4 st[4];
    if (ch+1 < NCH_){
#pragma unroll
      for (int k=0;k<4;k++)
        st[k] = *reinterpret_cast<const float4*>(
            W + (size_t)((ch+1)*CH_ + k*16+srr)*HN_ + h*BN_ + scc);
    }
    const float* sb = &sW[ch&1][0];
    int d0 = ch*CH_;
#pragma unroll 8
    for (int r=0;r<CH_;r++){
      float wd = sb[r*BN_ + lane];
#pragma unroll
      for (int i=0;i<PTT;i++)
        acc[i] = fmaf(xr[(size_t)i*D_ + d0 + r], wd, acc[i]);
    }
    if (ch+1 < NCH_){
#pragma unroll
      for (int k=0;k<4;k++)
        *reinterpret_cast<float4*>(&sW[(ch+1)&1][k*1024 + tid*4]) = st[k];
    }
    __syncthreads();
  }

  float bias = bb[h*BN_ + n];
#pragma unroll 1
  for (int i=0;i<PTT;i++){
    int t = t0 + i;
    double v = (double)(acc[i] + bias);
    if (mode < 2){
      const double2 cs2 = sTrig[(t - t0b)*32 + (n&31)];
      double vp = __shfl_xor(v, 32);
      double rot = (n<32) ? -vp : vp;
      v = v*cs2.x + rot*cs2.y;
    }
    // f64 lift (r12 lesson: must stay f64-computed; f32 storage safe)
    double ss = wsumd(v*v);
    double vn = sqrt(fmax(ss, TINY_));
    double e  = exp(vn);
    double ei = 1.0/e;
    double ch2 = 0.5*(e+ei);
    double s  = (0.5*(e-ei))/vn;               // sinh(vn)/vn
    double xx = s*s*ss - ch2*ch2;              // sum y^2 - ch^2 (exact algebra)
    double scale = sqrt(fmax(fabs(xx), TINY_));
    float y0 = (float)fabs(ch2/scale);
    float ya = (float)(s*v/scale);
    if (mode==0){
      float* o = Qf + (size_t)h*T_*QS_ + (size_t)t*QS_;
      if (n==0) o[0] = y0;
      o[n+1] = ya;
    } else if (mode==1){
      float* o = KTf + (size_t)h*66*KTS_ + t;
      if (n==0) o[0] = y0;
      o[(size_t)(n+1)*KTS_] = ya;
    } else {
      float* o = Vf + (size_t)h*T_*VS_ + (size_t)t*VS_;
      if (n==0) o[0] = y0;
      o[n+1] = ya;
      float* ot = VTf + (size_t)h*66*KTS_ + t;
      if (n==0) ot[0] = y0;
      ot[(size_t)(n+1)*KTS_] = ya;
    }
  }
}

// ---------------- kernel 2: attention; IT=4 + MERGED K^T/V^T dot phase (r19-exact)
__global__ __launch_bounds__(256) void k_attnF(
    const float* __restrict__ Qf, const float* __restrict__ KTf,
    const float* __restrict__ VTf, const float* __restrict__ Vf,
    const float* __restrict__ anchor, float* __restrict__ Z){
  __shared__ float  sYf[IT][QS_];     // Q rows f32 (epilogue casts to f64)
  __shared__ float  sYm[IT][SYS_];    // sign-folded f32, pads 0
  __shared__ float  s_w[IT][T_];      // scores -> attn -> w
  __shared__ double sA[A_];
  __shared__ float  s_red[4][IT];     // cY partials
  __shared__ float  s_part[4][IT][64];// w@V lane partials
  __shared__ float  s_p64[4][IT];     // w@V dim-64 partials

  int h = blockIdx.x, i0 = blockIdx.y*IT, tid = threadIdx.x;
  int wv = tid>>6, lane = tid&63;
  const float* Qp = Qf  + (size_t)h*T_*QS_;
  const float* KT = KTf + (size_t)h*66*KTS_;
  const float* VT = VTf + (size_t)h*66*KTS_;
  const float* Vp = Vf  + (size_t)h*T_*VS_;

  for (int f=tid; f<IT*QS_; f+=256){
    int i=f/QS_, a=f-i*QS_;
    sYf[i][a] = (a<A_) ? Qp[(size_t)(i0+i)*QS_ + a] : 0.f;
  }
  for (int f=tid; f<IT*SYS_; f+=256){
    int i=f/SYS_, a=f-i*SYS_;
    float v = (a<A_) ? Qp[(size_t)(i0+i)*QS_ + a] : 0.f;
    sYm[i][a] = (a==0) ? v : -v;
  }
  if (tid < A_) sA[tid] = (double)anchor[tid];
  __syncthreads();

  int j0 = tid, j1 = tid + 256;
  float avf0[IT], avf1[IT];           // alpha_yv, carried across softmax
  // ---- stage B (merged): alpha_qk AND alpha_yv via K^T/V^T in one pass
  {
    float aq0[IT], aq1[IT], av0[IT], av1[IT];
#pragma unroll
    for (int i=0;i<IT;i++){ aq0[i]=0.f; aq1[i]=0.f; av0[i]=0.f; av1[i]=0.f; }
    for (int a4=0; a4<16; a4++){
      int a = a4*4;
      float k00=KT[(size_t)(a+0)*KTS_+j0], k01=KT[(size_t)(a+1)*KTS_+j0];
      float k02=KT[(size_t)(a+2)*KTS_+j0], k03=KT[(size_t)(a+3)*KTS_+j0];
      float k10=KT[(size_t)(a+0)*KTS_+j1], k11=KT[(size_t)(a+1)*KTS_+j1];
      float k12=KT[(size_t)(a+2)*KTS_+j1], k13=KT[(size_t)(a+3)*KTS_+j1];
      float v00=VT[(size_t)(a+0)*KTS_+j0], v01=VT[(size_t)(a+1)*KTS_+j0];
      float v02=VT[(size_t)(a+2)*KTS_+j0], v03=VT[(size_t)(a+3)*KTS_+j0];
      float v10=VT[(size_t)(a+0)*KTS_+j1], v11=VT[(size_t)(a+1)*KTS_+j1];
      float v12=VT[(size_t)(a+2)*KTS_+j1], v13=VT[(size_t)(a+3)*KTS_+j1];
#pragma unroll
      for (int i=0;i<IT;i++){
        float4 ym = *reinterpret_cast<const float4*>(&sYm[i][a]);
        aq0[i] = fmaf(ym.w,k03,fmaf(ym.z,k02,fmaf(ym.y,k01,fmaf(ym.x,k00,aq0[i]))));
        aq1[i] = fmaf(ym.w,k13,fmaf(ym.z,k12,fmaf(ym.y,k11,fmaf(ym.x,k10,aq1[i]))));
        av0[i] = fmaf(ym.w,v03,fmaf(ym.z,v02,fmaf(ym.y,v01,fmaf(ym.x,v00,av0[i]))));
        av1[i] = fmaf(ym.w,v13,fmaf(ym.z,v12,fmaf(ym.y,v11,fmaf(ym.x,v10,av1[i]))));
      }
    }
    float kt0 = KT[(size_t)64*KTS_+j0], kt1 = KT[(size_t)64*KTS_+j1];
    float vt0 = VT[(size_t)64*KTS_+j0], vt1 = VT[(size_t)64*KTS_+j1];
#pragma unroll
    for (int i=0;i<IT;i++){
      float a0 = fmaf(sYm[i][64], kt0, aq0[i]);
      float a1 = fmaf(sYm[i][64], kt1, aq1[i]);
      float d0 = facoshf(fmaxf(a0, 1.f+EPSF_));
      float d1 = facoshf(fmaxf(a1, 1.f+EPSF_));
      s_w[i][j0] = -d0*d0;
      s_w[i][j1] = -d1*d1;
      avf0[i] = fmaf(sYm[i][64], vt0, av0[i]);
      avf1[i] = fmaf(sYm[i][64], vt1, av1[i]);
    }
  }
  __syncthreads();

  // ---- stage C: softmax (f32); wave wv owns row wv
  {
    int i = wv;
    float m = -INFINITY;
#pragma unroll
    for (int kk=0;kk<8;kk++) m = fmaxf(m, s_w[i][lane+64*kk]);
    m = wmaxf(m);
    float e[8], sum=0.f;
#pragma unroll
    for (int kk=0;kk<8;kk++){ e[kk]=__expf(s_w[i][lane+64*kk]-m); sum+=e[kk]; }
    sum = wsumf(sum);
    float inv = 1.f/sum;
#pragma unroll
    for (int kk=0;kk<8;kk++) s_w[i][lane+64*kk] = e[kk]*inv;
  }
  __syncthreads();

  // ---- stage B2 (pure VALU): w = attn*dist/un0; cY partials
  {
    const float inv_un0 = 3.16227766016838e7f;  // 1/sqrt(TINY); mink(u,u)<0 proven r4-r20
    float cyp[IT];
#pragma unroll
    for (int i=0;i<IT;i++){
      float at0 = s_w[i][j0], at1 = s_w[i][j1];
      float d0 = facoshf(fmaxf(avf0[i], 1.f+EPSF_));
      float d1 = facoshf(fmaxf(avf1[i], 1.f+EPSF_));
      float w0 = at0*d0*inv_un0;
      float w1 = at1*d1*inv_un0;
      s_w[i][j0] = w0;
      s_w[i][j1] = w1;
      cyp[i] = fmaf(w0, avf0[i], w1*avf1[i]);
    }
#pragma unroll
    for (int i=0;i<IT;i++){
      float r = wsumf(cyp[i]);
      if (lane==0) s_red[wv][i] = r;
    }
  }
  __syncthreads();

  // ---- stage D: w @ V, j-split (wave wv owns 128 j for ALL rows), j-quad float4 w reads
  {
    float pL[IT], p64r[IT];
#pragma unroll
    for (int i=0;i<IT;i++){ pL[i]=0.f; p64r[i]=0.f; }
    int jb = wv*128;
    for (int jj=0; jj<128; jj+=4){
      int j = jb + jj;
      float vA = Vp[(size_t)(j+0)*VS_ + lane];
      float vB = Vp[(size_t)(j+1)*VS_ + lane];
      float vC = Vp[(size_t)(j+2)*VS_ + lane];
      float vD = Vp[(size_t)(j+3)*VS_ + lane];
#pragma unroll
      for (int i=0;i<IT;i++){
        float4 w4 = *reinterpret_cast<const float4*>(&s_w[i][j]);
        pL[i] = fmaf(w4.w,vD,fmaf(w4.z,vC,fmaf(w4.y,vB,fmaf(w4.x,vA,pL[i]))));
      }
    }
#pragma unroll
    for (int cc=0; cc<2; cc++){
      int j = jb + cc*64 + lane;
      float v64 = VT[(size_t)64*KTS_ + j];
#pragma unroll
      for (int i=0;i<IT;i++) p64r[i] = fmaf(s_w[i][j], v64, p64r[i]);
    }
#pragma unroll
    for (int i=0;i<IT;i++){
      s_part[wv][i][lane] = pL[i];
      float r = wsumf(p64r[i]);
      if (lane==0) s_p64[wv][i] = r;
    }
  }
  __syncthreads();

  // ---- epilogue (f64 — deep mink cancellation lives here; proven r6-r20); row r = wv
  {
    int r = wv;
    double Yl  = (double)sYf[r][lane];
    double Y64 = (double)sYf[r][64];
    double cy = (double)s_red[0][r]+(double)s_red[1][r]+(double)s_red[2][r]+(double)s_red[3][r];
    double aL = (double)s_part[0][r][lane]+(double)s_part[1][r][lane]
              + (double)s_part[2][r][lane]+(double)s_part[3][r][lane];
    double a64 = (double)s_p64[0][r]+(double)s_p64[1][r]+(double)s_p64[2][r]+(double)s_p64[3][r];
    double ua  = fma(cy, Yl,  aL);
    double u64 = fma(cy, Y64, a64);
    double c2 = (lane==0) ? fma(u64,u64, -ua*ua) : ua*ua;
    double mv = wsumd(c2);
    double vn = sqrt(fmax(mv, TINY_));
    double ch = cosh(vn);
    double sh = sinh(vn)/fmax(vn, TINY_);
    double ya  = fma(ch, Yl,  sh*ua);
    double y64 = fma(ch, Y64, sh*u64);
    double c3 = (lane==0) ? fma(y64,y64, -ya*ya) : ya*ya;
    double px = wsumd(c3);
    double scale = sqrt(fmax(fabs(px), TINY_));
    double Pa  = ya/scale; if (lane==0) Pa = fabs(Pa);
    double P64 = y64/scale;
    double sAl = sA[lane];
    double azc = (lane==0) ? fma(sAl, Pa, -sA[64]*P64) : (-sAl*Pa);
    double az = wsumd(azc);
    double dz = acosh(fmax(az, 1.0+EPS_));
    double uza  = fma(az, sAl,    Pa);
    double uz64 = fma(az, sA[64], P64);
    double c4v = (lane==0) ? fma(uz64,uz64, -uza*uza) : uza*uza;
    double mz = wsumd(c4v);
    double unz = sqrt(fmax(mz, TINY_));
    double fz = dz/fmax(unz, TINY_);
    float* Zr = Z + (size_t)(i0+r)*HA_ + h*A_;
    Zr[lane] = (float)(fz*uza);
    if (lane==0) Zr[64] = (float)(fz*uz64);
  }
}

// ---------------- kernel 3: out = Z @ Wo + bo (f32); CTT=2 (r14 proven)
__global__ __launch_bounds__(256) void k_outD(
    const float* __restrict__ Zb, const float* __restrict__ Wo,
    const float* __restrict__ bo, float* __restrict__ out){
  int c  = blockIdx.x*256 + threadIdx.x;
  int t0 = blockIdx.y*CTT;
  float acc[CTT];
#pragma unroll
  for (int i=0;i<CTT;i++) acc[i]=0.f;
  for (int k=0;k<HA_;k+=4){
    float w0 = Wo[(size_t)(k+0)*D_ + c];
    float w1 = Wo[(size_t)(k+1)*D_ + c];
    float w2 = Wo[(size_t)(k+2)*D_ + c];
    float w3 = Wo[(size_t)(k+3)*D_ + c];
#pragma unroll
    for (int i=0;i<CTT;i++){
      const float* zr = Zb + (size_t)(t0+i)*HA_;
      acc[i] = fmaf(zr[k+0], w0, acc[i]);
      acc[i] = fmaf(zr[k+1], w1, acc[i]);
      acc[i] = fmaf(zr[k+2], w2, acc[i]);
      acc[i] = fmaf(zr[k+3], w3, acc[i]);
    }
  }
  float bb = bo[c];
#pragma unroll
  for (int i=0;i<CTT;i++) out[(t0+i)*D_ + c] = acc[i] + bb;
}

extern "C" void kernel_launch(void* const* d_in, const int* in_sizes, int n_in,
                              void* d_out, int out_size, void* d_ws, size_t ws_size,
                              hipStream_t stream){
  float* out = (float*)d_out;

  bool ok = (n_in == 10) && (out_size == T_*D_)
    && in_sizes[0]==T_*D_ && in_sizes[1]==D_*HN_ && in_sizes[2]==HN_
    && in_sizes[3]==D_*HN_ && in_sizes[4]==HN_
    && in_sizes[5]==D_*HN_ && in_sizes[6]==HN_
    && in_sizes[7]==HA_*D_ && in_sizes[8]==D_ && in_sizes[9]==A_;
  if (!ok){ k_fill<<<1024,256,0,stream>>>(out, 1.0e12f); return; }

  const float* x      = (const float*)d_in[0];
  const float* Wq     = (const float*)d_in[1];
  const float* bq     = (const float*)d_in[2];
  const float* Wk     = (const float*)d_in[3];
  const float* bk     = (const float*)d_in[4];
  const float* Wv     = (const float*)d_in[5];
  const float* bv     = (const float*)d_in[6];
  const float* Wo     = (const float*)d_in[7];
  const float* bo     = (const float*)d_in[8];
  const float* anchor = (const float*)d_in[9];
  char* ws = (char*)d_ws;

  size_t zbytes  = (size_t)T_*HA_*sizeof(float);            // 1,064,960
  size_t qbytes  = (size_t)H_*T_*QS_*sizeof(float);         // 1,081,344
  size_t ktbytes = (size_t)H_*66*KTS_*sizeof(float);        // 1,081,344
  size_t vbytes  = (size_t)H_*T_*VS_*sizeof(float);         // 1,081,344
  size_t vtbytes = (size_t)H_*66*KTS_*sizeof(float);        // 1,081,344
  size_t need    = zbytes+qbytes+ktbytes+vbytes+vtbytes;    // 5,390,336 <= proven 7,569,408
  if (ws_size < need){ k_fill<<<1024,256,0,stream>>>(out, 2.0e12f); return; }

  float*  Zf = (float*)ws;
  float*  Qf = (float*)(ws + zbytes);
  float*  KT = (float*)(ws + zbytes + qbytes);
  float*  Vf = (float*)(ws + zbytes + qbytes + ktbytes);
  float*  VT = (float*)(ws + zbytes + qbytes + ktbytes + vbytes);

  k_projlift<<<dim3(H_,3,T_/RPB_), 256, 0, stream>>>(x, Wq,bq, Wk,bk, Wv,bv, Qf, KT, Vf, VT);
  k_attnF   <<<dim3(H_, T_/IT),    256, 0, stream>>>(Qf, KT, VT, Vf, anchor, Zf);
  k_outD    <<<dim3(2, T_/CTT),    256, 0, stream>>>(Zf, Wo, bo, out);
}